// Round 1
// baseline (353.669 us; speedup 1.0000x reference)
//
#include <hip/hip_runtime.h>
#include <math.h>

// Weighted Pearson correlation over N=2^25 fp32 elements.
// Memory-bound streaming reduction: 384 MiB read -> floor ~64us @ 6.3 TB/s.
//
// Kernel 1: 2048 blocks x 256 thr, grid-stride float4 loads, 6 fp32
//           accumulators/thread, wave64 shuffle reduce + LDS cross-wave,
//           6 floats per block -> d_ws (layout [q][block] for coalesced
//           reads in kernel 2).
// Kernel 2: 1 block, double-precision sum of 2048 partials per quantity,
//           final formula in double, output fp32.

#define NBLK 2048
#define NTHR 256
#define NWAVE (NTHR / 64)

__global__ __launch_bounds__(NTHR) void corr_partial(
    const float4* __restrict__ xs4, const float4* __restrict__ ys4,
    const float4* __restrict__ ns4, const float* __restrict__ xs,
    const float* __restrict__ ys, const float* __restrict__ ns,
    float* __restrict__ partials, int n4, int n) {
  float s0 = 0.f, s1 = 0.f, s2 = 0.f, s3 = 0.f, s4 = 0.f, s5 = 0.f;

  const int tid = blockIdx.x * NTHR + threadIdx.x;
  const int stride = NBLK * NTHR;

  for (int i = tid; i < n4; i += stride) {
    float4 x = xs4[i];
    float4 y = ys4[i];
    float4 w = ns4[i];
#define ACC(c)                         \
    {                                  \
      s0 += w.c;                       \
      s1 = fmaf(w.c, x.c, s1);         \
      s2 = fmaf(w.c, y.c, s2);         \
      float wx = w.c * x.c;            \
      float wy = w.c * y.c;            \
      s3 = fmaf(wx, x.c, s3);          \
      s4 = fmaf(wy, y.c, s4);          \
      s5 = fmaf(wx, y.c, s5);          \
    }
    ACC(x) ACC(y) ACC(z) ACC(w)
#undef ACC
  }

  // Scalar tail (n not divisible by 4) — no-op for N = 2^25.
  for (int i = n4 * 4 + tid; i < n; i += stride) {
    float x = xs[i], y = ys[i], w = ns[i];
    s0 += w;
    s1 = fmaf(w, x, s1);
    s2 = fmaf(w, y, s2);
    float wx = w * x;
    float wy = w * y;
    s3 = fmaf(wx, x, s3);
    s4 = fmaf(wy, y, s4);
    s5 = fmaf(wx, y, s5);
  }

  // Wave64 butterfly-free down-shuffle reduce.
#pragma unroll
  for (int off = 32; off > 0; off >>= 1) {
    s0 += __shfl_down(s0, off, 64);
    s1 += __shfl_down(s1, off, 64);
    s2 += __shfl_down(s2, off, 64);
    s3 += __shfl_down(s3, off, 64);
    s4 += __shfl_down(s4, off, 64);
    s5 += __shfl_down(s5, off, 64);
  }

  __shared__ float red[NWAVE][6];
  const int wave = threadIdx.x >> 6;
  const int lane = threadIdx.x & 63;
  if (lane == 0) {
    red[wave][0] = s0; red[wave][1] = s1; red[wave][2] = s2;
    red[wave][3] = s3; red[wave][4] = s4; red[wave][5] = s5;
  }
  __syncthreads();
  if (threadIdx.x < 6) {
    float t = 0.f;
#pragma unroll
    for (int wv = 0; wv < NWAVE; ++wv) t += red[wv][threadIdx.x];
    // layout [quantity][block] so kernel 2 reads each quantity contiguously
    partials[threadIdx.x * NBLK + blockIdx.x] = t;
  }
}

__global__ __launch_bounds__(256) void corr_final(
    const float* __restrict__ partials, float* __restrict__ out) {
  double s[6] = {0, 0, 0, 0, 0, 0};
  for (int j = threadIdx.x; j < NBLK; j += 256) {
#pragma unroll
    for (int q = 0; q < 6; ++q) s[q] += (double)partials[q * NBLK + j];
  }
#pragma unroll
  for (int off = 32; off > 0; off >>= 1) {
#pragma unroll
    for (int q = 0; q < 6; ++q) s[q] += __shfl_down(s[q], off, 64);
  }
  __shared__ double red[4][6];
  const int wave = threadIdx.x >> 6;
  const int lane = threadIdx.x & 63;
  if (lane == 0) {
#pragma unroll
    for (int q = 0; q < 6; ++q) red[wave][q] = s[q];
  }
  __syncthreads();
  if (threadIdx.x == 0) {
    double sum_n = 0, sum_x = 0, sum_y = 0, sum_x2 = 0, sum_y2 = 0, sum_p = 0;
#pragma unroll
    for (int wv = 0; wv < 4; ++wv) {
      sum_n += red[wv][0]; sum_x += red[wv][1]; sum_y += red[wv][2];
      sum_x2 += red[wv][3]; sum_y2 += red[wv][4]; sum_p += red[wv][5];
    }
    double num = sum_n * sum_p - sum_x * sum_y;
    double den = sqrt(sum_n * sum_x2 - sum_x * sum_x) *
                 sqrt(sum_n * sum_y2 - sum_y * sum_y);
    out[0] = (float)(num / den);
  }
}

extern "C" void kernel_launch(void* const* d_in, const int* in_sizes, int n_in,
                              void* d_out, int out_size, void* d_ws, size_t ws_size,
                              hipStream_t stream) {
  const float* xs = (const float*)d_in[0];
  const float* ys = (const float*)d_in[1];
  const float* ns = (const float*)d_in[2];
  const int n = in_sizes[0];
  const int n4 = n / 4;
  float* partials = (float*)d_ws;  // 6 * NBLK floats = 48 KiB

  corr_partial<<<NBLK, NTHR, 0, stream>>>(
      (const float4*)xs, (const float4*)ys, (const float4*)ns,
      xs, ys, ns, partials, n4, n);
  corr_final<<<1, 256, 0, stream>>>(partials, (float*)d_out);
}